// Round 6
// baseline (326.617 us; speedup 1.0000x reference)
//
#include <hip/hip_runtime.h>

// B=4, H=W=64, D=256, N=8, K=V=32, H2=W2=32, HW=4096, M=1024 pooled/batch.

typedef _Float16 f16x8 __attribute__((ext_vector_type(8)));
typedef _Float16 f16x4 __attribute__((ext_vector_type(4)));
typedef float    f32x4 __attribute__((ext_vector_type(4)));

#define F16(x) static_cast<_Float16>(x)

#if __has_builtin(__builtin_amdgcn_exp2f)
#define EXP2(x) __builtin_amdgcn_exp2f(x)
#else
#define EXP2(x) exp2f(x)
#endif

// async global->LDS DMA, 16 B per lane; lane i lands at (uniform base) + i*16
__device__ __forceinline__ void gl_lds16(const void* g, void* l) {
    __builtin_amdgcn_global_load_lds(
        (const __attribute__((address_space(1))) unsigned int*)g,
        (__attribute__((address_space(3))) unsigned int*)l, 16, 0, 0);
}

// ---------------- prep: weight transpose + zero the combine workspace ------
// LDS 32x33 tile transpose: coalesced f32 reads along o, contiguous f16
// writes along d.  Also grid-stride zeroes gnum/gden/gtick (4.3 MB) so each
// graph replay self-resets the cross-block accumulators.
__global__ __launch_bounds__(256) void prep_kernel(
    const float* __restrict__ wq, const float* __restrict__ wk,
    const float* __restrict__ wv, _Float16* __restrict__ wt,
    float4* __restrict__ gz) {           // zero region, 270464 float4s
    __shared__ float t[32][33];
    const int blk = blockIdx.x;              // 192 = 3 mats x 64 tiles
    const int mat = blk >> 6;
    const int tile = blk & 63;
    const int d0 = (tile >> 3) * 32, o0 = (tile & 7) * 32;
    const float* w = (mat == 0) ? wq : (mat == 1 ? wk : wv);
    const int tx = threadIdx.x & 31, ty = threadIdx.x >> 5;   // ty 0..7

    // zero combine workspace (gnum 4 MB + gden 128 KB + gtick 2 KB)
    const float4 z4 = {0.f, 0.f, 0.f, 0.f};
    for (int i = blk * 256 + threadIdx.x; i < 270464; i += 192 * 256) gz[i] = z4;

#pragma unroll
    for (int i = 0; i < 4; ++i)
        t[ty + i * 8][tx] = w[(d0 + ty + i * 8) * 256 + o0 + tx];
    __syncthreads();
#pragma unroll
    for (int i = 0; i < 4; ++i)
        wt[(mat << 16) + (o0 + ty + i * 8) * 256 + d0 + tx] = (_Float16)t[tx][ty + i * 8];
}

// ---------------- proj: all three 1x1-conv GEMMs in one launch --------------
// block = 64 rows x 256 cols, 4 waves; wave = ALL 64 rows x 64 cols
// (4 mc x 4 nt).  A staged once per block in LDS (f16, double-buffered,
// depth-2 pipeline, raw lgkmcnt+barrier).
// V output written FRAGMENT-ORDERED for attn (vf layout, validated round 4):
//   vf[bn][key>>4][lam*8 + (v>>4)*4 + (key&3)], lam = (v&15) + ((key>>2)&3)*16.
__global__ __launch_bounds__(256) void proj_kernel(
    const float* __restrict__ blob, const _Float16* __restrict__ wt,
    const float* __restrict__ bq, const float* __restrict__ bk, const float* __restrict__ bv,
    _Float16* __restrict__ qo, _Float16* __restrict__ ko, _Float16* __restrict__ vo) {
    __shared__ __align__(16) char atile[2][4096];   // [buf][64 rows x 32 k f16]

    const int tid = threadIdx.x;
    const int lane = tid & 63, wid = tid >> 6;
    const int quad = lane >> 4, l16 = lane & 15;
    int jb = blockIdx.x;                     // 576 = 64 q + 256 k + 256 v
    int job, rowblk;
    if (jb < 64)       { job = 0; rowblk = jb; }
    else if (jb < 320) { job = 1; rowblk = jb - 64; }
    else               { job = 2; rowblk = jb - 320; }
    const int rowbase = rowblk * 64;
    const int colbase = wid * 64;
    const _Float16* wmat = wt + ((size_t)job << 16);
    const float* bias = (job == 0) ? bq : (job == 1 ? bk : bv);

    // ---- staging assignment: 256 threads x 16 B granule of the A tile ----
    const int srow = tid >> 2, sc8 = tid & 3;            // row 0..63, 8-elem col
    const int sslot = srow * 4 + ((sc8 + (srow >> 2)) & 3);
    const float* aptr;                                    // global src base
    if (job == 0) {
        const int grow = rowbase + srow;
        const int bb = grow >> 10, y = (grow >> 5) & 31, x = grow & 31;
        aptr = blob + (((bb * 64 + 2 * y) * 64) + 2 * x) * 256 + sc8 * 8;
    } else {
        aptr = blob + (size_t)(rowbase + srow) * 256 + sc8 * 8;
    }

    // per-wave weight pointers
    const _Float16* wptr[4];
#pragma unroll
    for (int nt = 0; nt < 4; ++nt)
        wptr[nt] = wmat + (size_t)(colbase + nt * 16 + l16) * 256 + quad * 8;

    // af read base (per-lane, swizzled; mc adds 1024 B)
    const int aread = l16 * 64 + ((quad + (l16 >> 2)) & 3) * 16;

    f32x4 acc[4][4];
#pragma unroll
    for (int mc = 0; mc < 4; ++mc)
#pragma unroll
        for (int nt = 0; nt < 4; ++nt) acc[mc][nt] = (f32x4){0.f, 0.f, 0.f, 0.f};

    f16x8 wf[2][4];      // weight double-buffer
    float4 ar[2][2];     // A-load double-buffer (8 f32 = one 16 B granule)

    auto A_LOAD = [&](int t, float4* dst) {
        const float* p = aptr + t * 32;
        if (job == 0) {
            float4 a0 = *(const float4*)(p);
            float4 a1 = *(const float4*)(p + 4);
            float4 b0 = *(const float4*)(p + 256);
            float4 b1 = *(const float4*)(p + 260);
            float4 c0 = *(const float4*)(p + 16384);
            float4 c1 = *(const float4*)(p + 16388);
            float4 d0 = *(const float4*)(p + 16640);
            float4 d1 = *(const float4*)(p + 16644);
            dst[0].x = fmaxf(fmaxf(a0.x, b0.x), fmaxf(c0.x, d0.x));
            dst[0].y = fmaxf(fmaxf(a0.y, b0.y), fmaxf(c0.y, d0.y));
            dst[0].z = fmaxf(fmaxf(a0.z, b0.z), fmaxf(c0.z, d0.z));
            dst[0].w = fmaxf(fmaxf(a0.w, b0.w), fmaxf(c0.w, d0.w));
            dst[1].x = fmaxf(fmaxf(a1.x, b1.x), fmaxf(c1.x, d1.x));
            dst[1].y = fmaxf(fmaxf(a1.y, b1.y), fmaxf(c1.y, d1.y));
            dst[1].z = fmaxf(fmaxf(a1.z, b1.z), fmaxf(c1.z, d1.z));
            dst[1].w = fmaxf(fmaxf(a1.w, b1.w), fmaxf(c1.w, d1.w));
        } else {
            dst[0] = *(const float4*)(p);
            dst[1] = *(const float4*)(p + 4);
        }
    };
    auto A_WRITE = [&](int buf, const float4* src) {
        auto c0 = __builtin_amdgcn_cvt_pkrtz(src[0].x, src[0].y);
        auto c1 = __builtin_amdgcn_cvt_pkrtz(src[0].z, src[0].w);
        auto c2 = __builtin_amdgcn_cvt_pkrtz(src[1].x, src[1].y);
        auto c3 = __builtin_amdgcn_cvt_pkrtz(src[1].z, src[1].w);
        f16x8 v = {F16(c0[0]), F16(c0[1]), F16(c1[0]), F16(c1[1]),
                   F16(c2[0]), F16(c2[1]), F16(c3[0]), F16(c3[1])};
        *(f16x8*)(atile[buf] + sslot * 16) = v;
    };
    auto W_LOAD = [&](int t, f16x8* dst) {
#pragma unroll
        for (int nt = 0; nt < 4; ++nt) dst[nt] = *(const f16x8*)(wptr[nt] + t * 32);
    };

    // ---- prologue ----
    W_LOAD(0, wf[0]);
    A_LOAD(0, ar[0]);
    A_WRITE(0, ar[0]);
    A_LOAD(1, ar[1]);
    asm volatile("s_waitcnt lgkmcnt(0)\n\ts_barrier" ::: "memory");

#pragma unroll
    for (int s = 0; s < 8; ++s) {
        if (s < 7) W_LOAD(s + 1, wf[(s + 1) & 1]);
        f16x8 af[4];
#pragma unroll
        for (int mc = 0; mc < 4; ++mc)
            af[mc] = *(const f16x8*)(atile[s & 1] + mc * 1024 + aread);
#pragma unroll
        for (int mc = 0; mc < 4; ++mc)
#pragma unroll
            for (int nt = 0; nt < 4; ++nt)
                acc[mc][nt] = __builtin_amdgcn_mfma_f32_16x16x32_f16(
                    af[mc], wf[s & 1][nt], acc[mc][nt], 0, 0, 0);
        if (s < 7) A_WRITE((s + 1) & 1, ar[(s + 1) & 1]);
        if (s < 6) A_LOAD(s + 2, ar[s & 1]);
        if (s < 7) asm volatile("s_waitcnt lgkmcnt(0)\n\ts_barrier" ::: "memory");
    }

    // ---- epilogue: bias / scale / swish + stores ----
#pragma unroll
    for (int nt = 0; nt < 4; ++nt) {
        const int o = colbase + nt * 16 + l16;
        const float bs = bias[o];
        const int nh = o >> 5, kk = o & 31;
#pragma unroll
        for (int mc = 0; mc < 4; ++mc) {
            if (job == 0) {
#pragma unroll
                for (int r = 0; r < 4; ++r) {
                    const int grow = rowbase + mc * 16 + quad * 4 + r;
                    // scale = (1/sqrt(32)) * log2(e): attn uses exp2
                    const float x = (acc[mc][nt][r] + bs) * 0.25503508f;
                    const int bb = grow >> 10, mm = grow & 1023;
                    qo[(((bb * 8 + nh) * 1024 + mm) << 5) + kk] = (_Float16)x;
                }
            } else if (job == 1) {
#pragma unroll
                for (int r = 0; r < 4; ++r) {
                    const int grow = rowbase + mc * 16 + quad * 4 + r;
                    const float x = acc[mc][nt][r] + bs;
                    const int bb = grow >> 12, ii = grow & 4095;
                    ko[(((bb * 8 + nh) * 4096 + ii) << 5) + kk] = (_Float16)x;
                }
            } else {
                // fragment-ordered V store: key = i0 + r, v = kk
                const int grow0 = rowbase + mc * 16 + quad * 4;
                const int bb = grow0 >> 12, i0 = grow0 & 4095;
                f16x4 pv;
#pragma unroll
                for (int r = 0; r < 4; ++r) {
                    float x = acc[mc][nt][r] + bs;
                    const float sg = 1.0f / (1.0f + __expf(-x));
                    pv[r] = (_Float16)(x * sg);
                }
                // lam = (kk&15) + ((i0>>2)&3)*16; (i0>>2)&3 == quad here
                *(f16x4*)(vo + (size_t)(bb * 8 + nh) * 131072 + (i0 >> 4) * 512
                             + ((kk & 15) + quad * 16) * 8 + (kk >> 4) * 4) = pv;
            }
        }
    }
}

// ---------------- attn: R5 pipeline, key-split ks=2, 3 blocks/CU ------------
// grid 1024 = 32 bn (XCD swizzle: bn%8==XCD) x 16 mt x 2 ks; block = 8 waves.
// Block (bn,mt,ks): q-rows [mt*64,+64), keys [ks*2048,+2048).
// wave (rg=wid&3, kc=wid>>2): 16 rows, kc stream = keys [ks*2048+kc*1024,+1024)
// = 16 steps of 64 keys, TRIPLE-buffered (LDS 48 KB -> 3 blocks/CU resident,
// 24 waves/CU -- grid-capped 16 waves/CU in round 5 was the stall source).
// Per step: issue 2 gl_lds16 for step s+2, compute step s, then raw
// s_waitcnt vmcnt(2) + s_barrier (counted: keeps s+2's loads in flight).
// LDS layouts linear in fragment order (round-4/5-validated): both main-loop
// reads are ds_read_b128 at lane*16 -> zero bank conflicts.
// Cross-block combine: both ks blocks atomicAdd num[64][32]/den[64] partials
// into gnum/gden (f32, zeroed by prep), fence, ticket; the SECOND arriver
// re-reads the sums (volatile, atomics are L2-coherent) and writes out.
__global__ __launch_bounds__(512, 6) void attn_kernel(
    const _Float16* __restrict__ qb,   // [32][1024][32] (pre-scaled log2e/sqrt32)
    const _Float16* __restrict__ kb,   // [32][4096][32]
    const _Float16* __restrict__ vf,   // [32][256][512] fragment-ordered halves
    float* __restrict__ out,           // [4][1024][256]
    float* __restrict__ gnum,          // [32][16][64][32]
    float* __restrict__ gden,          // [32][16][64]
    int*   __restrict__ gtick) {       // [32][16]
    __shared__ __align__(16) char pool[49152];   // 2 streams x 3 bufs x 8 KB

    const int tid = threadIdx.x;
    const int lane = tid & 63, wid = tid >> 6;
    const int quad = lane >> 4, l16 = lane & 15;
    const int bn = blockIdx.x & 31;
    const int mt = (blockIdx.x >> 5) & 15;
    const int ks = blockIdx.x >> 9;
    const int b = bn >> 3, n = bn & 7;
    const int m0 = mt * 64;
    const int rg = wid & 3, kc = wid >> 2;

    // ---- per-wave DMA assignments: 2 wave-loads (1 KB each) per step ----
    // j = 0..15: stream kcj = j>>3, sub = j&7; sub<4 -> K subtile sub,
    // sub>=4 -> V subtile sub-4.  Both sources advance 2048 elems/step.
    const _Float16* gsrc[2];
    int ldsoff[2];
#pragma unroll
    for (int jj = 0; jj < 2; ++jj) {
        const int j = wid + jj * 8;              // 0..15
        const int kcj = j >> 3, sub = j & 7;
        if (sub < 4) {   // K subtile: pre-swizzled source, linear LDS
            gsrc[jj] = kb + ((size_t)bn << 17)
                     + (size_t)(ks * 2048 + kcj * 1024 + sub * 16 + (lane & 15)) * 32
                     + (lane >> 4) * 8;
            ldsoff[jj] = kcj * 24576 + sub * 1024;
        } else {         // V subtile: vf is already fragment-ordered -> linear
            gsrc[jj] = vf + ((size_t)bn << 17)
                     + (size_t)(ks * 128 + kcj * 64 + (sub - 4)) * 512 + lane * 8;
            ldsoff[jj] = kcj * 24576 + 4096 + (sub - 4) * 1024;
        }
    }

    // Q fragment (16 rows, L2-hot)
    const f16x8 qf = *(const f16x8*)(qb + (((size_t)(bn << 10) + m0 + rg * 16 + l16) << 5) + quad * 8);

    // per-lane read base: both K and V reads are b128 at lane*16
    const int rbase = kc * 24576 + lane * 16;

    // prologue: DMA steps 0,1 into bufs 0,1
#pragma unroll
    for (int p = 0; p < 2; ++p)
#pragma unroll
        for (int jj = 0; jj < 2; ++jj) {
            gl_lds16(gsrc[jj], pool + ldsoff[jj] + p * 8192);
            gsrc[jj] += 2048;
        }
    asm volatile("s_waitcnt vmcnt(2)\n\ts_barrier" ::: "memory");   // step 0 ready

    f32x4 acc0 = (f32x4){0.f, 0.f, 0.f, 0.f};   // out^T[v=quad*4+r   ][m=rg*16+l16]
    f32x4 acc1 = acc0;                           // out^T[v=16+quad*4+r][m=rg*16+l16]
    float ps0 = 0.f;

    for (int s = 0; s < 16; ++s) {
        if (s < 14) {   // DMA step s+2 into buffer (s+2)%3
            const int nb = ((s + 2) % 3) * 8192;
#pragma unroll
            for (int jj = 0; jj < 2; ++jj) {
                gl_lds16(gsrc[jj], pool + ldsoff[jj] + nb);
                gsrc[jj] += 2048;
            }
        }
        const char* base = pool + rbase + (s % 3) * 8192;
#pragma unroll
        for (int tloc = 0; tloc < 4; ++tloc) {
            const f16x8 kf = *(const f16x8*)(base + tloc * 1024);
            const f16x8 vv = *(const f16x8*)(base + 4096 + tloc * 1024);
            const f16x4 va0 = {vv[0], vv[1], vv[2], vv[3]};
            const f16x4 va1 = {vv[4], vv[5], vv[6], vv[7]};

            f32x4 s0 = __builtin_amdgcn_mfma_f32_16x16x32_f16(kf, qf, (f32x4){0.f,0.f,0.f,0.f}, 0, 0, 0);
            const float p0 = EXP2(s0[0]), p1 = EXP2(s0[1]), p2 = EXP2(s0[2]), p3 = EXP2(s0[3]);
            ps0 += (p0 + p1) + (p2 + p3);
            auto e0 = __builtin_amdgcn_cvt_pkrtz(p0, p1);
            auto e1 = __builtin_amdgcn_cvt_pkrtz(p2, p3);
            const f16x4 pb = {F16(e0[0]), F16(e0[1]), F16(e1[0]), F16(e1[1])};
            acc0 = __builtin_amdgcn_mfma_f32_16x16x16f16(va0, pb, acc0, 0, 0, 0);
            acc1 = __builtin_amdgcn_mfma_f32_16x16x16f16(va1, pb, acc1, 0, 0, 0);
        }
        // wait for step s+1's loads (issued one full step ago), keep s+2's 2
        // loads in flight across the barrier
        if (s < 14)       asm volatile("s_waitcnt vmcnt(2)\n\ts_barrier" ::: "memory");
        else if (s == 14) asm volatile("s_waitcnt vmcnt(0)\n\ts_barrier" ::: "memory");
        else              asm volatile("s_barrier" ::: "memory");
    }

    // ---- epilogue 1: 2-way kc-split combine in (now free) LDS ----
    float* num = (float*)pool;                 // [64][33]
    float* den = (float*)(pool + 64 * 33 * 4); // [64]
    int*  fin  = (int*)(pool + 64 * 33 * 4 + 256);
    for (int i = tid; i < 64 * 33 + 64; i += 512) ((float*)pool)[i] = 0.f;
    __syncthreads();

    // sum exp-partials over the 4 quads (score rows live in quads)
    ps0 += __shfl_xor(ps0, 16); ps0 += __shfl_xor(ps0, 32);

    const int m = rg * 16 + l16;
#pragma unroll
    for (int r = 0; r < 4; ++r) {
        atomicAdd(&num[m * 33 + quad * 4 + r], acc0[r]);
        atomicAdd(&num[m * 33 + 16 + quad * 4 + r], acc1[r]);
    }
    if (quad == 0) atomicAdd(&den[m], ps0);
    __syncthreads();

    // ---- epilogue 2: cross-block (ks) combine via global accumulators ----
    const int gbase = bn * 16 + mt;
    float* gn = gnum + (size_t)gbase * 2048;   // [64][32]
    float* gd = gden + gbase * 64;
    const int mloc = tid >> 3, v4 = (tid & 7) * 4;
    {
        const float* nr = num + mloc * 33 + v4;
        atomicAdd(&gn[mloc * 32 + v4 + 0], nr[0]);
        atomicAdd(&gn[mloc * 32 + v4 + 1], nr[1]);
        atomicAdd(&gn[mloc * 32 + v4 + 2], nr[2]);
        atomicAdd(&gn[mloc * 32 + v4 + 3], nr[3]);
        if (tid < 64) atomicAdd(&gd[tid], den[tid]);
    }
    __threadfence();
    if (tid == 0) *fin = (atomicAdd(&gtick[gbase], 1) == 1);
    __syncthreads();
    if (!*fin) return;      // first arriver exits; second has all sums visible

    __threadfence();
    {
        volatile const float* vgn = gn;
        volatile const float* vgd = gd;
        const float inv = 1.0f / vgd[mloc];
        float4 o = {vgn[mloc * 32 + v4 + 0] * inv, vgn[mloc * 32 + v4 + 1] * inv,
                    vgn[mloc * 32 + v4 + 2] * inv, vgn[mloc * 32 + v4 + 3] * inv};
        *(float4*)(out + (((size_t)(b << 10) + m0 + mloc) << 8) + n * 32 + v4) = o;
    }
}

// ---------------- launch -----------------------------------------------------
extern "C" void kernel_launch(void* const* d_in, const int* in_sizes, int n_in,
                              void* d_out, int out_size, void* d_ws, size_t ws_size,
                              hipStream_t stream) {
    const float* blob = (const float*)d_in[0];
    const float* wq = (const float*)d_in[1];
    const float* bq = (const float*)d_in[2];
    const float* wk = (const float*)d_in[3];
    const float* bk = (const float*)d_in[4];
    const float* wv = (const float*)d_in[5];
    const float* bv = (const float*)d_in[6];
    float* out = (float*)d_out;

    char* ws = (char*)d_ws;
    _Float16* wt = (_Float16*)(ws);                    //   393,216 B
    _Float16* ko = (_Float16*)(ws + 393216);           // 8,388,608 B
    _Float16* vo = (_Float16*)(ws + 8781824);          // 8,388,608 B
    _Float16* qo = (_Float16*)(ws + 17170432);         // 2,097,152 B
    float*  gnum = (float*)(ws + 19267584);            // 4,194,304 B
    float*  gden = (float*)(ws + 23461888);            //   131,072 B
    int*   gtick = (int*)(ws + 23592960);              //     2,048 B

    prep_kernel<<<192, 256, 0, stream>>>(wq, wk, wv, wt, (float4*)(ws + 19267584));
    proj_kernel<<<576, 256, 0, stream>>>(blob, wt, bq, bk, bv, qo, ko, vo);
    attn_kernel<<<1024, 512, 0, stream>>>(qo, ko, vo, out, gnum, gden, gtick);
}

// Round 7
// 164.794 us; speedup vs baseline: 1.9820x; 1.9820x over previous
//
#include <hip/hip_runtime.h>

// B=4, H=W=64, D=256, N=8, K=V=32, H2=W2=32, HW=4096, M=1024 pooled/batch.

typedef _Float16 f16x8 __attribute__((ext_vector_type(8)));
typedef _Float16 f16x4 __attribute__((ext_vector_type(4)));
typedef float    f32x4 __attribute__((ext_vector_type(4)));

#define F16(x) static_cast<_Float16>(x)

#if __has_builtin(__builtin_amdgcn_exp2f)
#define EXP2(x) __builtin_amdgcn_exp2f(x)
#else
#define EXP2(x) exp2f(x)
#endif

// async global->LDS DMA, 16 B per lane; lane i lands at (uniform base) + i*16
__device__ __forceinline__ void gl_lds16(const void* g, void* l) {
    __builtin_amdgcn_global_load_lds(
        (const __attribute__((address_space(1))) unsigned int*)g,
        (__attribute__((address_space(3))) unsigned int*)l, 16, 0, 0);
}

// ---------------- prep: weights -> f16 transposed Wt[mat][o][d] -------------
// LDS 32x33 tile transpose: coalesced f32 reads along o, contiguous f16
// writes along d.
__global__ __launch_bounds__(256) void prep_kernel(
    const float* __restrict__ wq, const float* __restrict__ wk,
    const float* __restrict__ wv, _Float16* __restrict__ wt) {
    __shared__ float t[32][33];
    const int blk = blockIdx.x;              // 192 = 3 mats x 64 tiles
    const int mat = blk >> 6;
    const int tile = blk & 63;
    const int d0 = (tile >> 3) * 32, o0 = (tile & 7) * 32;
    const float* w = (mat == 0) ? wq : (mat == 1 ? wk : wv);
    const int tx = threadIdx.x & 31, ty = threadIdx.x >> 5;   // ty 0..7
#pragma unroll
    for (int i = 0; i < 4; ++i)
        t[ty + i * 8][tx] = w[(d0 + ty + i * 8) * 256 + o0 + tx];
    __syncthreads();
#pragma unroll
    for (int i = 0; i < 4; ++i)
        wt[(mat << 16) + (o0 + ty + i * 8) * 256 + d0 + tx] = (_Float16)t[tx][ty + i * 8];
}

// ---------------- proj: all three 1x1-conv GEMMs in one launch --------------
// block = 64 rows x 256 cols, 4 waves; wave = ALL 64 rows x 64 cols
// (4 mc x 4 nt).  A staged once per block in LDS (f16, double-buffered,
// depth-2 pipeline, raw lgkmcnt+barrier).
// V output written FRAGMENT-ORDERED for attn (vf layout, validated round 4):
//   vf[bn][key>>4][lam*8 + (v>>4)*4 + (key&3)], lam = (v&15) + ((key>>2)&3)*16.
__global__ __launch_bounds__(256) void proj_kernel(
    const float* __restrict__ blob, const _Float16* __restrict__ wt,
    const float* __restrict__ bq, const float* __restrict__ bk, const float* __restrict__ bv,
    _Float16* __restrict__ qo, _Float16* __restrict__ ko, _Float16* __restrict__ vo) {
    __shared__ __align__(16) char atile[2][4096];   // [buf][64 rows x 32 k f16]

    const int tid = threadIdx.x;
    const int lane = tid & 63, wid = tid >> 6;
    const int quad = lane >> 4, l16 = lane & 15;
    int jb = blockIdx.x;                     // 576 = 64 q + 256 k + 256 v
    int job, rowblk;
    if (jb < 64)       { job = 0; rowblk = jb; }
    else if (jb < 320) { job = 1; rowblk = jb - 64; }
    else               { job = 2; rowblk = jb - 320; }
    const int rowbase = rowblk * 64;
    const int colbase = wid * 64;
    const _Float16* wmat = wt + ((size_t)job << 16);
    const float* bias = (job == 0) ? bq : (job == 1 ? bk : bv);

    // ---- staging assignment: 256 threads x 16 B granule of the A tile ----
    const int srow = tid >> 2, sc8 = tid & 3;            // row 0..63, 8-elem col
    const int sslot = srow * 4 + ((sc8 + (srow >> 2)) & 3);
    const float* aptr;                                    // global src base
    if (job == 0) {
        const int grow = rowbase + srow;
        const int bb = grow >> 10, y = (grow >> 5) & 31, x = grow & 31;
        aptr = blob + (((bb * 64 + 2 * y) * 64) + 2 * x) * 256 + sc8 * 8;
    } else {
        aptr = blob + (size_t)(rowbase + srow) * 256 + sc8 * 8;
    }

    // per-wave weight pointers
    const _Float16* wptr[4];
#pragma unroll
    for (int nt = 0; nt < 4; ++nt)
        wptr[nt] = wmat + (size_t)(colbase + nt * 16 + l16) * 256 + quad * 8;

    // af read base (per-lane, swizzled; mc adds 1024 B)
    const int aread = l16 * 64 + ((quad + (l16 >> 2)) & 3) * 16;

    f32x4 acc[4][4];
#pragma unroll
    for (int mc = 0; mc < 4; ++mc)
#pragma unroll
        for (int nt = 0; nt < 4; ++nt) acc[mc][nt] = (f32x4){0.f, 0.f, 0.f, 0.f};

    f16x8 wf[2][4];      // weight double-buffer
    float4 ar[2][2];     // A-load double-buffer (8 f32 = one 16 B granule)

    auto A_LOAD = [&](int t, float4* dst) {
        const float* p = aptr + t * 32;
        if (job == 0) {
            float4 a0 = *(const float4*)(p);
            float4 a1 = *(const float4*)(p + 4);
            float4 b0 = *(const float4*)(p + 256);
            float4 b1 = *(const float4*)(p + 260);
            float4 c0 = *(const float4*)(p + 16384);
            float4 c1 = *(const float4*)(p + 16388);
            float4 d0 = *(const float4*)(p + 16640);
            float4 d1 = *(const float4*)(p + 16644);
            dst[0].x = fmaxf(fmaxf(a0.x, b0.x), fmaxf(c0.x, d0.x));
            dst[0].y = fmaxf(fmaxf(a0.y, b0.y), fmaxf(c0.y, d0.y));
            dst[0].z = fmaxf(fmaxf(a0.z, b0.z), fmaxf(c0.z, d0.z));
            dst[0].w = fmaxf(fmaxf(a0.w, b0.w), fmaxf(c0.w, d0.w));
            dst[1].x = fmaxf(fmaxf(a1.x, b1.x), fmaxf(c1.x, d1.x));
            dst[1].y = fmaxf(fmaxf(a1.y, b1.y), fmaxf(c1.y, d1.y));
            dst[1].z = fmaxf(fmaxf(a1.z, b1.z), fmaxf(c1.z, d1.z));
            dst[1].w = fmaxf(fmaxf(a1.w, b1.w), fmaxf(c1.w, d1.w));
        } else {
            dst[0] = *(const float4*)(p);
            dst[1] = *(const float4*)(p + 4);
        }
    };
    auto A_WRITE = [&](int buf, const float4* src) {
        auto c0 = __builtin_amdgcn_cvt_pkrtz(src[0].x, src[0].y);
        auto c1 = __builtin_amdgcn_cvt_pkrtz(src[0].z, src[0].w);
        auto c2 = __builtin_amdgcn_cvt_pkrtz(src[1].x, src[1].y);
        auto c3 = __builtin_amdgcn_cvt_pkrtz(src[1].z, src[1].w);
        f16x8 v = {F16(c0[0]), F16(c0[1]), F16(c1[0]), F16(c1[1]),
                   F16(c2[0]), F16(c2[1]), F16(c3[0]), F16(c3[1])};
        *(f16x8*)(atile[buf] + sslot * 16) = v;
    };
    auto W_LOAD = [&](int t, f16x8* dst) {
#pragma unroll
        for (int nt = 0; nt < 4; ++nt) dst[nt] = *(const f16x8*)(wptr[nt] + t * 32);
    };

    // ---- prologue ----
    W_LOAD(0, wf[0]);
    A_LOAD(0, ar[0]);
    A_WRITE(0, ar[0]);
    A_LOAD(1, ar[1]);
    asm volatile("s_waitcnt lgkmcnt(0)\n\ts_barrier" ::: "memory");

#pragma unroll
    for (int s = 0; s < 8; ++s) {
        if (s < 7) W_LOAD(s + 1, wf[(s + 1) & 1]);
        f16x8 af[4];
#pragma unroll
        for (int mc = 0; mc < 4; ++mc)
            af[mc] = *(const f16x8*)(atile[s & 1] + mc * 1024 + aread);
#pragma unroll
        for (int mc = 0; mc < 4; ++mc)
#pragma unroll
            for (int nt = 0; nt < 4; ++nt)
                acc[mc][nt] = __builtin_amdgcn_mfma_f32_16x16x32_f16(
                    af[mc], wf[s & 1][nt], acc[mc][nt], 0, 0, 0);
        if (s < 7) A_WRITE((s + 1) & 1, ar[(s + 1) & 1]);
        if (s < 6) A_LOAD(s + 2, ar[s & 1]);
        if (s < 7) asm volatile("s_waitcnt lgkmcnt(0)\n\ts_barrier" ::: "memory");
    }

    // ---- epilogue: bias / scale / swish + stores ----
#pragma unroll
    for (int nt = 0; nt < 4; ++nt) {
        const int o = colbase + nt * 16 + l16;
        const float bs = bias[o];
        const int nh = o >> 5, kk = o & 31;
#pragma unroll
        for (int mc = 0; mc < 4; ++mc) {
            if (job == 0) {
#pragma unroll
                for (int r = 0; r < 4; ++r) {
                    const int grow = rowbase + mc * 16 + quad * 4 + r;
                    // scale = (1/sqrt(32)) * log2(e): attn uses exp2
                    const float x = (acc[mc][nt][r] + bs) * 0.25503508f;
                    const int bb = grow >> 10, mm = grow & 1023;
                    qo[(((bb * 8 + nh) * 1024 + mm) << 5) + kk] = (_Float16)x;
                }
            } else if (job == 1) {
#pragma unroll
                for (int r = 0; r < 4; ++r) {
                    const int grow = rowbase + mc * 16 + quad * 4 + r;
                    const float x = acc[mc][nt][r] + bs;
                    const int bb = grow >> 12, ii = grow & 4095;
                    ko[(((bb * 8 + nh) * 4096 + ii) << 5) + kk] = (_Float16)x;
                }
            } else {
                // fragment-ordered V store: key = i0 + r, v = kk
                const int grow0 = rowbase + mc * 16 + quad * 4;
                const int bb = grow0 >> 12, i0 = grow0 & 4095;
                f16x4 pv;
#pragma unroll
                for (int r = 0; r < 4; ++r) {
                    float x = acc[mc][nt][r] + bs;
                    const float sg = 1.0f / (1.0f + __expf(-x));
                    pv[r] = (_Float16)(x * sg);
                }
                // lam = (kk&15) + ((i0>>2)&3)*16; (i0>>2)&3 == quad here
                *(f16x4*)(vo + (size_t)(bb * 8 + nh) * 131072 + (i0 >> 4) * 512
                             + ((kk & 15) + quad * 16) * 8 + (kk >> 4) * 4) = pv;
            }
        }
    }
}

// ---------------- attn: R5 pipeline, dedup'd LDS reads, 4 row-chains/wave ---
// grid 512 = 32 bn (XCD swizzle: bn%8==XCD) x 16 mt; block = 8 waves, 64 rows.
// wave (kc=wid&1, ks=wid>>1): stream kc = keys [kc*2048,+2048), and within
// every 64-key step this wave owns ONLY subtile tloc=ks (16 keys) but ALL 64
// q-rows (qf[4], acc[4][2]).  vs round 5 (4 waves re-reading the same tile):
//   - LDS reads per wave-step: 8 -> 2 (zero cross-wave redundancy)
//   - 4 independent {QK->exp->pack->PV} chains per step (was 1) -> ILP hides
//     ds_read/MFMA/exp latency at the same occupancy.
// MFMA/exp totals unchanged.  DMA assignment, LDS layout, triple-buffered
// vmcnt(2)+s_barrier schedule, epilogue: byte-identical to round 5 (verified).
// Round-6 lesson: NO cross-block combine -- fences/device atomics thrash the
// non-coherent per-XCD L2s and stall the DMA streams (45.8 -> 239 us).
__global__ __launch_bounds__(512, 4) void attn_kernel(
    const _Float16* __restrict__ qb,   // [32][1024][32] (pre-scaled log2e/sqrt32)
    const _Float16* __restrict__ kb,   // [32][4096][32]
    const _Float16* __restrict__ vf,   // [32][256][512] fragment-ordered halves
    float* __restrict__ out) {         // [4][1024][256]
    __shared__ __align__(16) char pool[49152];   // 2 streams x 3 bufs x 8 KB

    const int tid = threadIdx.x;
    const int lane = tid & 63, wid = tid >> 6;
    const int quad = lane >> 4, l16 = lane & 15;
    const int bn = blockIdx.x & 31, mt = blockIdx.x >> 5;
    const int b = bn >> 3, n = bn & 7;
    const int m0 = mt * 64;
    const int kc = wid & 1, ks = wid >> 1;   // stream, fixed 16-key subtile

    // ---- per-wave DMA assignments: 2 wave-loads (1 KB each) per step ----
    // j = 0..15: stream kcj = j>>3, sub = j&7; sub<4 -> K subtile sub,
    // sub>=4 -> V subtile sub-4.  Both sources advance 2048 elems/step.
    const _Float16* gsrc[2];
    int ldsoff[2];
#pragma unroll
    for (int jj = 0; jj < 2; ++jj) {
        const int j = wid + jj * 8;              // 0..15
        const int kcj = j >> 3, sub = j & 7;
        if (sub < 4) {   // K subtile: pre-swizzled source, linear LDS
            gsrc[jj] = kb + ((size_t)bn << 17)
                     + (size_t)(kcj * 2048 + sub * 16 + (lane & 15)) * 32 + (lane >> 4) * 8;
            ldsoff[jj] = kcj * 24576 + sub * 1024;
        } else {         // V subtile: vf is already fragment-ordered -> linear
            gsrc[jj] = vf + ((size_t)bn << 17)
                     + (size_t)(kcj * 128 + (sub - 4)) * 512 + lane * 8;
            ldsoff[jj] = kcj * 24576 + 4096 + (sub - 4) * 1024;
        }
    }

    // Q fragments: all 4 row-groups (L2-hot)
    f16x8 qf[4];
#pragma unroll
    for (int g = 0; g < 4; ++g)
        qf[g] = *(const f16x8*)(qb + (((size_t)(bn << 10) + m0 + g * 16 + l16) << 5) + quad * 8);

    // per-lane read bases: this wave's fixed subtile, b128 at lane*16
    const int kread = kc * 24576 + ks * 1024 + lane * 16;
    const int vread = kread + 4096;

    // prologue: DMA steps 0,1 into bufs 0,1
#pragma unroll
    for (int p = 0; p < 2; ++p)
#pragma unroll
        for (int jj = 0; jj < 2; ++jj) {
            gl_lds16(gsrc[jj], pool + ldsoff[jj] + p * 8192);
            gsrc[jj] += 2048;
        }
    asm volatile("s_waitcnt vmcnt(2)\n\ts_barrier" ::: "memory");   // step 0 ready

    f32x4 acc[4][2];   // [g][vc]: out^T[v=vc*16+quad*4+r][m=g*16+l16]
#pragma unroll
    for (int g = 0; g < 4; ++g) {
        acc[g][0] = (f32x4){0.f, 0.f, 0.f, 0.f};
        acc[g][1] = acc[g][0];
    }
    float ps[4] = {0.f, 0.f, 0.f, 0.f};

    for (int s = 0; s < 32; ++s) {
        if (s < 30) {   // DMA step s+2 into buffer (s+2)%3
            const int nb = ((s + 2) % 3) * 8192;
#pragma unroll
            for (int jj = 0; jj < 2; ++jj) {
                gl_lds16(gsrc[jj], pool + ldsoff[jj] + nb);
                gsrc[jj] += 2048;
            }
        }
        const int bo = (s % 3) * 8192;
        const f16x8 kf = *(const f16x8*)(pool + kread + bo);
        const f16x8 vv = *(const f16x8*)(pool + vread + bo);
        const f16x4 va0 = {vv[0], vv[1], vv[2], vv[3]};
        const f16x4 va1 = {vv[4], vv[5], vv[6], vv[7]};
#pragma unroll
        for (int g = 0; g < 4; ++g) {
            f32x4 s0 = __builtin_amdgcn_mfma_f32_16x16x32_f16(kf, qf[g], (f32x4){0.f,0.f,0.f,0.f}, 0, 0, 0);
            const float p0 = EXP2(s0[0]), p1 = EXP2(s0[1]), p2 = EXP2(s0[2]), p3 = EXP2(s0[3]);
            ps[g] += (p0 + p1) + (p2 + p3);
            auto e0 = __builtin_amdgcn_cvt_pkrtz(p0, p1);
            auto e1 = __builtin_amdgcn_cvt_pkrtz(p2, p3);
            const f16x4 pb = {F16(e0[0]), F16(e0[1]), F16(e1[0]), F16(e1[1])};
            acc[g][0] = __builtin_amdgcn_mfma_f32_16x16x16f16(va0, pb, acc[g][0], 0, 0, 0);
            acc[g][1] = __builtin_amdgcn_mfma_f32_16x16x16f16(va1, pb, acc[g][1], 0, 0, 0);
        }
        // wait for step s+1's loads (issued one full step ago), keep s+2's 2
        // loads in flight across the barrier
        if (s < 30)       asm volatile("s_waitcnt vmcnt(2)\n\ts_barrier" ::: "memory");
        else if (s == 30) asm volatile("s_waitcnt vmcnt(0)\n\ts_barrier" ::: "memory");
        else              asm volatile("s_barrier" ::: "memory");
    }

    // ---- epilogue: 8-way (kc,ks)-split combine in (now free) LDS ----
    float* num = (float*)pool;                 // [64][33]
    float* den = (float*)(pool + 64 * 33 * 4); // [64]
    for (int i = tid; i < 64 * 33 + 64; i += 512) ((float*)pool)[i] = 0.f;
    __syncthreads();

    // sum exp-partials over the 4 quads (score rows live in quads)
#pragma unroll
    for (int g = 0; g < 4; ++g) {
        ps[g] += __shfl_xor(ps[g], 16);
        ps[g] += __shfl_xor(ps[g], 32);
    }

#pragma unroll
    for (int g = 0; g < 4; ++g) {
        const int m = g * 16 + l16;
#pragma unroll
        for (int r = 0; r < 4; ++r) {
            atomicAdd(&num[m * 33 + quad * 4 + r], acc[g][0][r]);
            atomicAdd(&num[m * 33 + 16 + quad * 4 + r], acc[g][1][r]);
        }
        if (quad == 0) atomicAdd(&den[m], ps[g]);
    }
    __syncthreads();

    // store: 64 m x 32 v = 2048 f32 = 512 threads x one float4
    {
        const int mloc = tid >> 3, v4 = (tid & 7) * 4;
        const float inv = 1.0f / den[mloc];
        const float* nr = num + mloc * 33 + v4;
        float4 o = {nr[0] * inv, nr[1] * inv, nr[2] * inv, nr[3] * inv};
        *(float4*)(out + (((size_t)(b << 10) + m0 + mloc) << 8) + n * 32 + v4) = o;
    }
}

// ---------------- launch -----------------------------------------------------
extern "C" void kernel_launch(void* const* d_in, const int* in_sizes, int n_in,
                              void* d_out, int out_size, void* d_ws, size_t ws_size,
                              hipStream_t stream) {
    const float* blob = (const float*)d_in[0];
    const float* wq = (const float*)d_in[1];
    const float* bq = (const float*)d_in[2];
    const float* wk = (const float*)d_in[3];
    const float* bk = (const float*)d_in[4];
    const float* wv = (const float*)d_in[5];
    const float* bv = (const float*)d_in[6];
    float* out = (float*)d_out;

    char* ws = (char*)d_ws;
    _Float16* wt = (_Float16*)(ws);                    //   393,216 B
    _Float16* ko = (_Float16*)(ws + 393216);           // 8,388,608 B
    _Float16* vo = (_Float16*)(ws + 8781824);          // 8,388,608 B
    _Float16* qo = (_Float16*)(ws + 17170432);         // 2,097,152 B

    prep_kernel<<<192, 256, 0, stream>>>(wq, wk, wv, wt);
    proj_kernel<<<576, 256, 0, stream>>>(blob, wt, bq, bk, bv, qo, ko, vo);
    attn_kernel<<<512, 512, 0, stream>>>(qo, ko, vo, out);
}

// Round 8
// 142.534 us; speedup vs baseline: 2.2915x; 1.1562x over previous
//
#include <hip/hip_runtime.h>

// B=4, H=W=64, D=256, N=8, K=V=32, H2=W2=32, HW=4096, M=1024 pooled/batch.

typedef _Float16 f16x8 __attribute__((ext_vector_type(8)));
typedef _Float16 f16x4 __attribute__((ext_vector_type(4)));
typedef float    f32x4 __attribute__((ext_vector_type(4)));

#define F16(x) static_cast<_Float16>(x)

#if __has_builtin(__builtin_amdgcn_exp2f)
#define EXP2(x) __builtin_amdgcn_exp2f(x)
#else
#define EXP2(x) exp2f(x)
#endif

// async global->LDS DMA, 16 B per lane; lane i lands at (uniform base) + i*16
__device__ __forceinline__ void gl_lds16(const void* g, void* l) {
    __builtin_amdgcn_global_load_lds(
        (const __attribute__((address_space(1))) unsigned int*)g,
        (__attribute__((address_space(3))) unsigned int*)l, 16, 0, 0);
}

// ---------------- prep: weights -> f16 transposed Wt[mat][o][d] -------------
// LDS 32x33 tile transpose: coalesced f32 reads along o, contiguous f16
// writes along d.
__global__ __launch_bounds__(256) void prep_kernel(
    const float* __restrict__ wq, const float* __restrict__ wk,
    const float* __restrict__ wv, _Float16* __restrict__ wt) {
    __shared__ float t[32][33];
    const int blk = blockIdx.x;              // 192 = 3 mats x 64 tiles
    const int mat = blk >> 6;
    const int tile = blk & 63;
    const int d0 = (tile >> 3) * 32, o0 = (tile & 7) * 32;
    const float* w = (mat == 0) ? wq : (mat == 1 ? wk : wv);
    const int tx = threadIdx.x & 31, ty = threadIdx.x >> 5;   // ty 0..7
#pragma unroll
    for (int i = 0; i < 4; ++i)
        t[ty + i * 8][tx] = w[(d0 + ty + i * 8) * 256 + o0 + tx];
    __syncthreads();
#pragma unroll
    for (int i = 0; i < 4; ++i)
        wt[(mat << 16) + (o0 + ty + i * 8) * 256 + d0 + tx] = (_Float16)t[tx][ty + i * 8];
}

// ---------------- proj: all three 1x1-conv GEMMs in one launch --------------
// block = 32 rows x 256 cols, 4 waves; wave = ALL 32 rows x 64 cols
// (2 mc x 4 nt).  vs round-5's 64-row blocks: grid 576 -> 1152 raises
// occupancy 2.25 -> 4.5 blocks/CU (9 -> 18 waves/CU) -- proj was grid-capped,
// both pipes <10% busy.  A staged once per block in LDS (f16, double-buffered
// 2x2KB, depth-2 pipeline, raw lgkmcnt+barrier, staging by tid<128 only).
// V output written FRAGMENT-ORDERED for attn (vf layout, validated round 4):
//   vf[bn][key>>4][lam*8 + (v>>4)*4 + (key&3)], lam = (v&15) + ((key>>2)&3)*16.
__global__ __launch_bounds__(256) void proj_kernel(
    const float* __restrict__ blob, const _Float16* __restrict__ wt,
    const float* __restrict__ bq, const float* __restrict__ bk, const float* __restrict__ bv,
    _Float16* __restrict__ qo, _Float16* __restrict__ ko, _Float16* __restrict__ vo) {
    __shared__ __align__(16) char atile[2][2048];   // [buf][32 rows x 32 k f16]

    const int tid = threadIdx.x;
    const int lane = tid & 63, wid = tid >> 6;
    const int quad = lane >> 4, l16 = lane & 15;
    int jb = blockIdx.x;                     // 1152 = 128 q + 512 k + 512 v
    int job, rowblk;
    if (jb < 128)      { job = 0; rowblk = jb; }
    else if (jb < 640) { job = 1; rowblk = jb - 128; }
    else               { job = 2; rowblk = jb - 640; }
    const int rowbase = rowblk * 32;
    const int colbase = wid * 64;
    const _Float16* wmat = wt + ((size_t)job << 16);
    const float* bias = (job == 0) ? bq : (job == 1 ? bk : bv);

    // ---- staging assignment: threads 0..127 x 16 B granule of the A tile ----
    const bool stager = tid < 128;
    const int srow = tid >> 2, sc8 = tid & 3;            // row 0..31, 8-elem col
    const int sslot = srow * 4 + ((sc8 + (srow >> 2)) & 3);
    const float* aptr;                                    // global src base
    if (job == 0) {
        const int grow = rowbase + (srow & 31);
        const int bb = grow >> 10, y = (grow >> 5) & 31, x = grow & 31;
        aptr = blob + (((bb * 64 + 2 * y) * 64) + 2 * x) * 256 + sc8 * 8;
    } else {
        aptr = blob + (size_t)(rowbase + (srow & 31)) * 256 + sc8 * 8;
    }

    // per-wave weight pointers
    const _Float16* wptr[4];
#pragma unroll
    for (int nt = 0; nt < 4; ++nt)
        wptr[nt] = wmat + (size_t)(colbase + nt * 16 + l16) * 256 + quad * 8;

    // af read base (per-lane, swizzled; mc adds 1024 B)
    const int aread = l16 * 64 + ((quad + (l16 >> 2)) & 3) * 16;

    f32x4 acc[2][4];
#pragma unroll
    for (int mc = 0; mc < 2; ++mc)
#pragma unroll
        for (int nt = 0; nt < 4; ++nt) acc[mc][nt] = (f32x4){0.f, 0.f, 0.f, 0.f};

    f16x8 wf[2][4];      // weight double-buffer
    float4 ar[2][2];     // A-load double-buffer (8 f32 = one 16 B granule)

    auto A_LOAD = [&](int t, float4* dst) {
        if (!stager) return;
        const float* p = aptr + t * 32;
        if (job == 0) {
            float4 a0 = *(const float4*)(p);
            float4 a1 = *(const float4*)(p + 4);
            float4 b0 = *(const float4*)(p + 256);
            float4 b1 = *(const float4*)(p + 260);
            float4 c0 = *(const float4*)(p + 16384);
            float4 c1 = *(const float4*)(p + 16388);
            float4 d0 = *(const float4*)(p + 16640);
            float4 d1 = *(const float4*)(p + 16644);
            dst[0].x = fmaxf(fmaxf(a0.x, b0.x), fmaxf(c0.x, d0.x));
            dst[0].y = fmaxf(fmaxf(a0.y, b0.y), fmaxf(c0.y, d0.y));
            dst[0].z = fmaxf(fmaxf(a0.z, b0.z), fmaxf(c0.z, d0.z));
            dst[0].w = fmaxf(fmaxf(a0.w, b0.w), fmaxf(c0.w, d0.w));
            dst[1].x = fmaxf(fmaxf(a1.x, b1.x), fmaxf(c1.x, d1.x));
            dst[1].y = fmaxf(fmaxf(a1.y, b1.y), fmaxf(c1.y, d1.y));
            dst[1].z = fmaxf(fmaxf(a1.z, b1.z), fmaxf(c1.z, d1.z));
            dst[1].w = fmaxf(fmaxf(a1.w, b1.w), fmaxf(c1.w, d1.w));
        } else {
            dst[0] = *(const float4*)(p);
            dst[1] = *(const float4*)(p + 4);
        }
    };
    auto A_WRITE = [&](int buf, const float4* src) {
        if (!stager) return;
        auto c0 = __builtin_amdgcn_cvt_pkrtz(src[0].x, src[0].y);
        auto c1 = __builtin_amdgcn_cvt_pkrtz(src[0].z, src[0].w);
        auto c2 = __builtin_amdgcn_cvt_pkrtz(src[1].x, src[1].y);
        auto c3 = __builtin_amdgcn_cvt_pkrtz(src[1].z, src[1].w);
        f16x8 v = {F16(c0[0]), F16(c0[1]), F16(c1[0]), F16(c1[1]),
                   F16(c2[0]), F16(c2[1]), F16(c3[0]), F16(c3[1])};
        *(f16x8*)(atile[buf] + sslot * 16) = v;
    };
    auto W_LOAD = [&](int t, f16x8* dst) {
#pragma unroll
        for (int nt = 0; nt < 4; ++nt) dst[nt] = *(const f16x8*)(wptr[nt] + t * 32);
    };

    // ---- prologue ----
    W_LOAD(0, wf[0]);
    A_LOAD(0, ar[0]);
    A_WRITE(0, ar[0]);
    A_LOAD(1, ar[1]);
    asm volatile("s_waitcnt lgkmcnt(0)\n\ts_barrier" ::: "memory");

#pragma unroll
    for (int s = 0; s < 8; ++s) {
        if (s < 7) W_LOAD(s + 1, wf[(s + 1) & 1]);
        f16x8 af[2];
#pragma unroll
        for (int mc = 0; mc < 2; ++mc)
            af[mc] = *(const f16x8*)(atile[s & 1] + mc * 1024 + aread);
#pragma unroll
        for (int mc = 0; mc < 2; ++mc)
#pragma unroll
            for (int nt = 0; nt < 4; ++nt)
                acc[mc][nt] = __builtin_amdgcn_mfma_f32_16x16x32_f16(
                    af[mc], wf[s & 1][nt], acc[mc][nt], 0, 0, 0);
        if (s < 7) A_WRITE((s + 1) & 1, ar[(s + 1) & 1]);
        if (s < 6) A_LOAD(s + 2, ar[s & 1]);
        if (s < 7) asm volatile("s_waitcnt lgkmcnt(0)\n\ts_barrier" ::: "memory");
    }

    // ---- epilogue: bias / scale / swish + stores ----
#pragma unroll
    for (int nt = 0; nt < 4; ++nt) {
        const int o = colbase + nt * 16 + l16;
        const float bs = bias[o];
        const int nh = o >> 5, kk = o & 31;
#pragma unroll
        for (int mc = 0; mc < 2; ++mc) {
            if (job == 0) {
#pragma unroll
                for (int r = 0; r < 4; ++r) {
                    const int grow = rowbase + mc * 16 + quad * 4 + r;
                    // scale = (1/sqrt(32)) * log2(e): attn uses exp2
                    const float x = (acc[mc][nt][r] + bs) * 0.25503508f;
                    const int bb = grow >> 10, mm = grow & 1023;
                    qo[(((bb * 8 + nh) * 1024 + mm) << 5) + kk] = (_Float16)x;
                }
            } else if (job == 1) {
#pragma unroll
                for (int r = 0; r < 4; ++r) {
                    const int grow = rowbase + mc * 16 + quad * 4 + r;
                    const float x = acc[mc][nt][r] + bs;
                    const int bb = grow >> 12, ii = grow & 4095;
                    ko[(((bb * 8 + nh) * 4096 + ii) << 5) + kk] = (_Float16)x;
                }
            } else {
                // fragment-ordered V store: key = i0 + r, v = kk
                const int grow0 = rowbase + mc * 16 + quad * 4;
                const int bb = grow0 >> 12, i0 = grow0 & 4095;
                f16x4 pv;
#pragma unroll
                for (int r = 0; r < 4; ++r) {
                    float x = acc[mc][nt][r] + bs;
                    const float sg = 1.0f / (1.0f + __expf(-x));
                    pv[r] = (_Float16)(x * sg);
                }
                // lam = (kk&15) + ((i0>>2)&3)*16; (i0>>2)&3 == quad here
                *(f16x4*)(vo + (size_t)(bb * 8 + nh) * 131072 + (i0 >> 4) * 512
                             + ((kk & 15) + quad * 16) * 8 + (kk >> 4) * 4) = pv;
            }
        }
    }
}

// ---------------- attn: R5 pipeline (verified 45.8 us), byte-exact revert ---
// grid 512 = 32 bn (XCD swizzle: bn%8==XCD) x 16 mt; block = 8 waves, 64 rows.
// wave (rg=wid&3, kc=wid>>2): q-rows [m0+rg*16,+16), keys [kc*2048,+2048).
// 2 shared K/V streams, each TRIPLE-buffered 64-key tiles (32 steps):
//   stream base kc*24576 + buf*8192: K tile 4 KB | V tile 4 KB,
//   each as 4 x 1 KB fragment-ordered subtiles (16 keys).
// Per step each wave issues 2 gl_lds16 for step s+2, computes step s, then
//   s_waitcnt vmcnt(2) + s_barrier  (raw asm: keeps s+2's loads in flight
//   across the barrier -- the counted-vmcnt pipeline).
// Both main-loop reads are ds_read_b128 at lane*16 -> zero bank conflicts.
// Round-6 lesson: NO cross-block combine (fences thrash non-coherent L2s).
// Round-7 lesson: keep 4 tloc chains per wave-step (private ds_reads) --
// dedup'd single-subtile waves serialize on one load root and regress.
__global__ __launch_bounds__(512, 4) void attn_kernel(
    const _Float16* __restrict__ qb,   // [32][1024][32] (pre-scaled log2e/sqrt32)
    const _Float16* __restrict__ kb,   // [32][4096][32]
    const _Float16* __restrict__ vf,   // [32][256][512] fragment-ordered halves
    float* __restrict__ out) {         // [4][1024][256]
    __shared__ __align__(16) char pool[49152];   // 2 streams x 3 bufs x 8 KB

    const int tid = threadIdx.x;
    const int lane = tid & 63, wid = tid >> 6;
    const int quad = lane >> 4, l16 = lane & 15;
    const int bn = blockIdx.x & 31, mt = blockIdx.x >> 5;
    const int b = bn >> 3, n = bn & 7;
    const int m0 = mt * 64;
    const int rg = wid & 3, kc = wid >> 2;

    // ---- per-wave DMA assignments: 2 wave-loads (1 KB each) per step ----
    // j = 0..15: stream kcj = j>>3, sub = j&7; sub<4 -> K subtile sub,
    // sub>=4 -> V subtile sub-4.  Both sources advance 2048 elems/step.
    const _Float16* gsrc[2];
    int ldsoff[2];
#pragma unroll
    for (int jj = 0; jj < 2; ++jj) {
        const int j = wid + jj * 8;              // 0..15
        const int kcj = j >> 3, sub = j & 7;
        if (sub < 4) {   // K subtile: pre-swizzled source, linear LDS
            gsrc[jj] = kb + ((size_t)bn << 17)
                     + (size_t)(kcj * 2048 + sub * 16 + (lane & 15)) * 32 + (lane >> 4) * 8;
            ldsoff[jj] = kcj * 24576 + sub * 1024;
        } else {         // V subtile: vf is already fragment-ordered -> linear
            gsrc[jj] = vf + ((size_t)bn << 17)
                     + (size_t)(kcj * 128 + (sub - 4)) * 512 + lane * 8;
            ldsoff[jj] = kcj * 24576 + 4096 + (sub - 4) * 1024;
        }
    }

    // Q fragment (16 rows, L2-hot)
    const f16x8 qf = *(const f16x8*)(qb + (((size_t)(bn << 10) + m0 + rg * 16 + l16) << 5) + quad * 8);

    // per-lane read base: both K and V reads are b128 at lane*16
    const int rbase = kc * 24576 + lane * 16;

    // prologue: DMA steps 0,1 into bufs 0,1
#pragma unroll
    for (int p = 0; p < 2; ++p)
#pragma unroll
        for (int jj = 0; jj < 2; ++jj) {
            gl_lds16(gsrc[jj], pool + ldsoff[jj] + p * 8192);
            gsrc[jj] += 2048;
        }
    asm volatile("s_waitcnt vmcnt(2)\n\ts_barrier" ::: "memory");   // step 0 ready

    f32x4 acc0 = (f32x4){0.f, 0.f, 0.f, 0.f};   // out^T[v=quad*4+r   ][m=rg*16+l16]
    f32x4 acc1 = acc0;                           // out^T[v=16+quad*4+r][m=rg*16+l16]
    float ps0 = 0.f;

    for (int s = 0; s < 32; ++s) {
        if (s < 30) {   // DMA step s+2 into buffer (s+2)%3
            const int nb = ((s + 2) % 3) * 8192;
#pragma unroll
            for (int jj = 0; jj < 2; ++jj) {
                gl_lds16(gsrc[jj], pool + ldsoff[jj] + nb);
                gsrc[jj] += 2048;
            }
        }
        const char* base = pool + rbase + (s % 3) * 8192;
#pragma unroll
        for (int tloc = 0; tloc < 4; ++tloc) {
            const f16x8 kf = *(const f16x8*)(base + tloc * 1024);
            const f16x8 vv = *(const f16x8*)(base + 4096 + tloc * 1024);
            const f16x4 va0 = {vv[0], vv[1], vv[2], vv[3]};
            const f16x4 va1 = {vv[4], vv[5], vv[6], vv[7]};

            f32x4 s0 = __builtin_amdgcn_mfma_f32_16x16x32_f16(kf, qf, (f32x4){0.f,0.f,0.f,0.f}, 0, 0, 0);
            const float p0 = EXP2(s0[0]), p1 = EXP2(s0[1]), p2 = EXP2(s0[2]), p3 = EXP2(s0[3]);
            ps0 += (p0 + p1) + (p2 + p3);
            auto e0 = __builtin_amdgcn_cvt_pkrtz(p0, p1);
            auto e1 = __builtin_amdgcn_cvt_pkrtz(p2, p3);
            const f16x4 pb = {F16(e0[0]), F16(e0[1]), F16(e1[0]), F16(e1[1])};
            acc0 = __builtin_amdgcn_mfma_f32_16x16x16f16(va0, pb, acc0, 0, 0, 0);
            acc1 = __builtin_amdgcn_mfma_f32_16x16x16f16(va1, pb, acc1, 0, 0, 0);
        }
        // wait for step s+1's loads (issued one full step ago), keep s+2's 2
        // loads in flight across the barrier
        if (s < 30)       asm volatile("s_waitcnt vmcnt(2)\n\ts_barrier" ::: "memory");
        else if (s == 30) asm volatile("s_waitcnt vmcnt(0)\n\ts_barrier" ::: "memory");
        else              asm volatile("s_barrier" ::: "memory");
    }

    // ---- epilogue: 2-way key-split combine in (now free) LDS ----
    float* num = (float*)pool;                 // [64][33]
    float* den = (float*)(pool + 64 * 33 * 4); // [64]
    for (int i = tid; i < 64 * 33 + 64; i += 512) ((float*)pool)[i] = 0.f;
    __syncthreads();

    // sum exp-partials over the 4 quads (score rows live in quads)
    ps0 += __shfl_xor(ps0, 16); ps0 += __shfl_xor(ps0, 32);

    const int m = rg * 16 + l16;
#pragma unroll
    for (int r = 0; r < 4; ++r) {
        atomicAdd(&num[m * 33 + quad * 4 + r], acc0[r]);
        atomicAdd(&num[m * 33 + 16 + quad * 4 + r], acc1[r]);
    }
    if (quad == 0) atomicAdd(&den[m], ps0);
    __syncthreads();

    // store: 64 m x 32 v = 2048 f32 = 512 threads x one float4
    {
        const int mloc = tid >> 3, v4 = (tid & 7) * 4;
        const float inv = 1.0f / den[mloc];
        const float* nr = num + mloc * 33 + v4;
        float4 o = {nr[0] * inv, nr[1] * inv, nr[2] * inv, nr[3] * inv};
        *(float4*)(out + (((size_t)(b << 10) + m0 + mloc) << 8) + n * 32 + v4) = o;
    }
}

// ---------------- launch -----------------------------------------------------
extern "C" void kernel_launch(void* const* d_in, const int* in_sizes, int n_in,
                              void* d_out, int out_size, void* d_ws, size_t ws_size,
                              hipStream_t stream) {
    const float* blob = (const float*)d_in[0];
    const float* wq = (const float*)d_in[1];
    const float* bq = (const float*)d_in[2];
    const float* wk = (const float*)d_in[3];
    const float* bk = (const float*)d_in[4];
    const float* wv = (const float*)d_in[5];
    const float* bv = (const float*)d_in[6];
    float* out = (float*)d_out;

    char* ws = (char*)d_ws;
    _Float16* wt = (_Float16*)(ws);                    //   393,216 B
    _Float16* ko = (_Float16*)(ws + 393216);           // 8,388,608 B
    _Float16* vo = (_Float16*)(ws + 8781824);          // 8,388,608 B
    _Float16* qo = (_Float16*)(ws + 17170432);         // 2,097,152 B

    prep_kernel<<<192, 256, 0, stream>>>(wq, wk, wv, wt);
    proj_kernel<<<1152, 256, 0, stream>>>(blob, wt, bq, bk, bv, qo, ko, vo);
    attn_kernel<<<512, 512, 0, stream>>>(qo, ko, vo, out);
}

// Round 9
// 134.298 us; speedup vs baseline: 2.4320x; 1.0613x over previous
//
#include <hip/hip_runtime.h>

// B=4, H=W=64, D=256, N=8, K=V=32, H2=W2=32, HW=4096, M=1024 pooled/batch.

typedef _Float16 f16x8 __attribute__((ext_vector_type(8)));
typedef _Float16 f16x4 __attribute__((ext_vector_type(4)));
typedef float    f32x4 __attribute__((ext_vector_type(4)));

#define F16(x) static_cast<_Float16>(x)

#if __has_builtin(__builtin_amdgcn_exp2f)
#define EXP2(x) __builtin_amdgcn_exp2f(x)
#else
#define EXP2(x) exp2f(x)
#endif

// async global->LDS DMA, 16 B per lane; lane i lands at (uniform base) + i*16
__device__ __forceinline__ void gl_lds16(const void* g, void* l) {
    __builtin_amdgcn_global_load_lds(
        (const __attribute__((address_space(1))) unsigned int*)g,
        (__attribute__((address_space(3))) unsigned int*)l, 16, 0, 0);
}

// ---------------- prep: weights -> f16 transposed Wt[mat][o][d] -------------
// LDS 32x33 tile transpose: coalesced f32 reads along o, contiguous f16
// writes along d.
__global__ __launch_bounds__(256) void prep_kernel(
    const float* __restrict__ wq, const float* __restrict__ wk,
    const float* __restrict__ wv, _Float16* __restrict__ wt) {
    __shared__ float t[32][33];
    const int blk = blockIdx.x;              // 192 = 3 mats x 64 tiles
    const int mat = blk >> 6;
    const int tile = blk & 63;
    const int d0 = (tile >> 3) * 32, o0 = (tile & 7) * 32;
    const float* w = (mat == 0) ? wq : (mat == 1 ? wk : wv);
    const int tx = threadIdx.x & 31, ty = threadIdx.x >> 5;   // ty 0..7
#pragma unroll
    for (int i = 0; i < 4; ++i)
        t[ty + i * 8][tx] = w[(d0 + ty + i * 8) * 256 + o0 + tx];
    __syncthreads();
#pragma unroll
    for (int i = 0; i < 4; ++i)
        wt[(mat << 16) + (o0 + ty + i * 8) * 256 + d0 + tx] = (_Float16)t[tx][ty + i * 8];
}

// ---------------- proj: all three 1x1-conv GEMMs in one launch --------------
// block = 64 rows x 256 cols, 4 waves; wave = ALL 64 rows x 64 cols
// (4 mc x 4 nt).  Verified R5 structure (measured ~26 us inside the 133.8
// total).  ONE change this round: W register ring 2 -> 3 buffers, prefetch
// distance 1 -> 2 steps (W consumed ~150-200 cyc after issue was < L2-hit
// latency ~300-500 cyc -> every step ate a W stall; R8 showed occupancy is
// NOT the lever -- 32-row blocks doubled W traffic and regressed 7 us).
// A staged once per block in LDS (f16, double-buffered 2x4KB, depth-2
// pipeline, raw lgkmcnt+barrier).  V output written FRAGMENT-ORDERED for
// attn (vf layout, validated round 4):
//   vf[bn][key>>4][lam*8 + (v>>4)*4 + (key&3)], lam = (v&15) + ((key>>2)&3)*16.
__global__ __launch_bounds__(256) void proj_kernel(
    const float* __restrict__ blob, const _Float16* __restrict__ wt,
    const float* __restrict__ bq, const float* __restrict__ bk, const float* __restrict__ bv,
    _Float16* __restrict__ qo, _Float16* __restrict__ ko, _Float16* __restrict__ vo) {
    __shared__ __align__(16) char atile[2][4096];   // [buf][64 rows x 32 k f16]

    const int tid = threadIdx.x;
    const int lane = tid & 63, wid = tid >> 6;
    const int quad = lane >> 4, l16 = lane & 15;
    int jb = blockIdx.x;                     // 576 = 64 q + 256 k + 256 v
    int job, rowblk;
    if (jb < 64)       { job = 0; rowblk = jb; }
    else if (jb < 320) { job = 1; rowblk = jb - 64; }
    else               { job = 2; rowblk = jb - 320; }
    const int rowbase = rowblk * 64;
    const int colbase = wid * 64;
    const _Float16* wmat = wt + ((size_t)job << 16);
    const float* bias = (job == 0) ? bq : (job == 1 ? bk : bv);

    // ---- staging assignment: 256 threads x 16 B granule of the A tile ----
    const int srow = tid >> 2, sc8 = tid & 3;            // row 0..63, 8-elem col
    const int sslot = srow * 4 + ((sc8 + (srow >> 2)) & 3);
    const float* aptr;                                    // global src base
    if (job == 0) {
        const int grow = rowbase + srow;
        const int bb = grow >> 10, y = (grow >> 5) & 31, x = grow & 31;
        aptr = blob + (((bb * 64 + 2 * y) * 64) + 2 * x) * 256 + sc8 * 8;
    } else {
        aptr = blob + (size_t)(rowbase + srow) * 256 + sc8 * 8;
    }

    // per-wave weight pointers
    const _Float16* wptr[4];
#pragma unroll
    for (int nt = 0; nt < 4; ++nt)
        wptr[nt] = wmat + (size_t)(colbase + nt * 16 + l16) * 256 + quad * 8;

    // af read base (per-lane, swizzled; mc adds 1024 B)
    const int aread = l16 * 64 + ((quad + (l16 >> 2)) & 3) * 16;

    f32x4 acc[4][4];
#pragma unroll
    for (int mc = 0; mc < 4; ++mc)
#pragma unroll
        for (int nt = 0; nt < 4; ++nt) acc[mc][nt] = (f32x4){0.f, 0.f, 0.f, 0.f};

    f16x8 wf[3][4];      // weight TRIPLE buffer (2-step prefetch distance)
    float4 ar[2][2];     // A-load double-buffer (8 f32 = one 16 B granule)

    auto A_LOAD = [&](int t, float4* dst) {
        const float* p = aptr + t * 32;
        if (job == 0) {
            float4 a0 = *(const float4*)(p);
            float4 a1 = *(const float4*)(p + 4);
            float4 b0 = *(const float4*)(p + 256);
            float4 b1 = *(const float4*)(p + 260);
            float4 c0 = *(const float4*)(p + 16384);
            float4 c1 = *(const float4*)(p + 16388);
            float4 d0 = *(const float4*)(p + 16640);
            float4 d1 = *(const float4*)(p + 16644);
            dst[0].x = fmaxf(fmaxf(a0.x, b0.x), fmaxf(c0.x, d0.x));
            dst[0].y = fmaxf(fmaxf(a0.y, b0.y), fmaxf(c0.y, d0.y));
            dst[0].z = fmaxf(fmaxf(a0.z, b0.z), fmaxf(c0.z, d0.z));
            dst[0].w = fmaxf(fmaxf(a0.w, b0.w), fmaxf(c0.w, d0.w));
            dst[1].x = fmaxf(fmaxf(a1.x, b1.x), fmaxf(c1.x, d1.x));
            dst[1].y = fmaxf(fmaxf(a1.y, b1.y), fmaxf(c1.y, d1.y));
            dst[1].z = fmaxf(fmaxf(a1.z, b1.z), fmaxf(c1.z, d1.z));
            dst[1].w = fmaxf(fmaxf(a1.w, b1.w), fmaxf(c1.w, d1.w));
        } else {
            dst[0] = *(const float4*)(p);
            dst[1] = *(const float4*)(p + 4);
        }
    };
    auto A_WRITE = [&](int buf, const float4* src) {
        auto c0 = __builtin_amdgcn_cvt_pkrtz(src[0].x, src[0].y);
        auto c1 = __builtin_amdgcn_cvt_pkrtz(src[0].z, src[0].w);
        auto c2 = __builtin_amdgcn_cvt_pkrtz(src[1].x, src[1].y);
        auto c3 = __builtin_amdgcn_cvt_pkrtz(src[1].z, src[1].w);
        f16x8 v = {F16(c0[0]), F16(c0[1]), F16(c1[0]), F16(c1[1]),
                   F16(c2[0]), F16(c2[1]), F16(c3[0]), F16(c3[1])};
        *(f16x8*)(atile[buf] + sslot * 16) = v;
    };
    auto W_LOAD = [&](int t, f16x8* dst) {
#pragma unroll
        for (int nt = 0; nt < 4; ++nt) dst[nt] = *(const f16x8*)(wptr[nt] + t * 32);
    };

    // ---- prologue: W 2 steps deep, A depth-2 ----
    W_LOAD(0, wf[0]);
    W_LOAD(1, wf[1]);
    A_LOAD(0, ar[0]);
    A_WRITE(0, ar[0]);
    A_LOAD(1, ar[1]);
    asm volatile("s_waitcnt lgkmcnt(0)\n\ts_barrier" ::: "memory");

#pragma unroll
    for (int s = 0; s < 8; ++s) {
        if (s < 6) W_LOAD(s + 2, wf[(s + 2) % 3]);   // 2-step W lookahead
        f16x8 af[4];
#pragma unroll
        for (int mc = 0; mc < 4; ++mc)
            af[mc] = *(const f16x8*)(atile[s & 1] + mc * 1024 + aread);
#pragma unroll
        for (int mc = 0; mc < 4; ++mc)
#pragma unroll
            for (int nt = 0; nt < 4; ++nt)
                acc[mc][nt] = __builtin_amdgcn_mfma_f32_16x16x32_f16(
                    af[mc], wf[s % 3][nt], acc[mc][nt], 0, 0, 0);
        if (s < 7) A_WRITE((s + 1) & 1, ar[(s + 1) & 1]);
        if (s < 6) A_LOAD(s + 2, ar[s & 1]);
        if (s < 7) asm volatile("s_waitcnt lgkmcnt(0)\n\ts_barrier" ::: "memory");
    }

    // ---- epilogue: bias / scale / swish + stores ----
#pragma unroll
    for (int nt = 0; nt < 4; ++nt) {
        const int o = colbase + nt * 16 + l16;
        const float bs = bias[o];
        const int nh = o >> 5, kk = o & 31;
#pragma unroll
        for (int mc = 0; mc < 4; ++mc) {
            if (job == 0) {
#pragma unroll
                for (int r = 0; r < 4; ++r) {
                    const int grow = rowbase + mc * 16 + quad * 4 + r;
                    // scale = (1/sqrt(32)) * log2(e): attn uses exp2
                    const float x = (acc[mc][nt][r] + bs) * 0.25503508f;
                    const int bb = grow >> 10, mm = grow & 1023;
                    qo[(((bb * 8 + nh) * 1024 + mm) << 5) + kk] = (_Float16)x;
                }
            } else if (job == 1) {
#pragma unroll
                for (int r = 0; r < 4; ++r) {
                    const int grow = rowbase + mc * 16 + quad * 4 + r;
                    const float x = acc[mc][nt][r] + bs;
                    const int bb = grow >> 12, ii = grow & 4095;
                    ko[(((bb * 8 + nh) * 4096 + ii) << 5) + kk] = (_Float16)x;
                }
            } else {
                // fragment-ordered V store: key = i0 + r, v = kk
                const int grow0 = rowbase + mc * 16 + quad * 4;
                const int bb = grow0 >> 12, i0 = grow0 & 4095;
                f16x4 pv;
#pragma unroll
                for (int r = 0; r < 4; ++r) {
                    float x = acc[mc][nt][r] + bs;
                    const float sg = 1.0f / (1.0f + __expf(-x));
                    pv[r] = (_Float16)(x * sg);
                }
                // lam = (kk&15) + ((i0>>2)&3)*16; (i0>>2)&3 == quad here
                *(f16x4*)(vo + (size_t)(bb * 8 + nh) * 131072 + (i0 >> 4) * 512
                             + ((kk & 15) + quad * 16) * 8 + (kk >> 4) * 4) = pv;
            }
        }
    }
}

// ---------------- attn: R5 pipeline (verified 45.8-47.3 us), unchanged ------
// grid 512 = 32 bn (XCD swizzle: bn%8==XCD) x 16 mt; block = 8 waves, 64 rows.
// wave (rg=wid&3, kc=wid>>2): q-rows [m0+rg*16,+16), keys [kc*2048,+2048).
// 2 shared K/V streams, each TRIPLE-buffered 64-key tiles (32 steps):
//   stream base kc*24576 + buf*8192: K tile 4 KB | V tile 4 KB,
//   each as 4 x 1 KB fragment-ordered subtiles (16 keys).
// Per step each wave issues 2 gl_lds16 for step s+2, computes step s, then
//   s_waitcnt vmcnt(2) + s_barrier  (raw asm: keeps s+2's loads in flight
//   across the barrier -- the counted-vmcnt pipeline).
// Both main-loop reads are ds_read_b128 at lane*16 -> zero bank conflicts.
// Round-6 lesson: NO cross-block combine (fences thrash non-coherent L2s).
// Round-7 lesson: keep 4 tloc chains per wave-step (private ds_reads) --
// dedup'd single-subtile waves serialize on one load root and regress.
__global__ __launch_bounds__(512, 4) void attn_kernel(
    const _Float16* __restrict__ qb,   // [32][1024][32] (pre-scaled log2e/sqrt32)
    const _Float16* __restrict__ kb,   // [32][4096][32]
    const _Float16* __restrict__ vf,   // [32][256][512] fragment-ordered halves
    float* __restrict__ out) {         // [4][1024][256]
    __shared__ __align__(16) char pool[49152];   // 2 streams x 3 bufs x 8 KB

    const int tid = threadIdx.x;
    const int lane = tid & 63, wid = tid >> 6;
    const int quad = lane >> 4, l16 = lane & 15;
    const int bn = blockIdx.x & 31, mt = blockIdx.x >> 5;
    const int b = bn >> 3, n = bn & 7;
    const int m0 = mt * 64;
    const int rg = wid & 3, kc = wid >> 2;

    // ---- per-wave DMA assignments: 2 wave-loads (1 KB each) per step ----
    // j = 0..15: stream kcj = j>>3, sub = j&7; sub<4 -> K subtile sub,
    // sub>=4 -> V subtile sub-4.  Both sources advance 2048 elems/step.
    const _Float16* gsrc[2];
    int ldsoff[2];
#pragma unroll
    for (int jj = 0; jj < 2; ++jj) {
        const int j = wid + jj * 8;              // 0..15
        const int kcj = j >> 3, sub = j & 7;
        if (sub < 4) {   // K subtile: pre-swizzled source, linear LDS
            gsrc[jj] = kb + ((size_t)bn << 17)
                     + (size_t)(kcj * 2048 + sub * 16 + (lane & 15)) * 32 + (lane >> 4) * 8;
            ldsoff[jj] = kcj * 24576 + sub * 1024;
        } else {         // V subtile: vf is already fragment-ordered -> linear
            gsrc[jj] = vf + ((size_t)bn << 17)
                     + (size_t)(kcj * 128 + (sub - 4)) * 512 + lane * 8;
            ldsoff[jj] = kcj * 24576 + 4096 + (sub - 4) * 1024;
        }
    }

    // Q fragment (16 rows, L2-hot)
    const f16x8 qf = *(const f16x8*)(qb + (((size_t)(bn << 10) + m0 + rg * 16 + l16) << 5) + quad * 8);

    // per-lane read base: both K and V reads are b128 at lane*16
    const int rbase = kc * 24576 + lane * 16;

    // prologue: DMA steps 0,1 into bufs 0,1
#pragma unroll
    for (int p = 0; p < 2; ++p)
#pragma unroll
        for (int jj = 0; jj < 2; ++jj) {
            gl_lds16(gsrc[jj], pool + ldsoff[jj] + p * 8192);
            gsrc[jj] += 2048;
        }
    asm volatile("s_waitcnt vmcnt(2)\n\ts_barrier" ::: "memory");   // step 0 ready

    f32x4 acc0 = (f32x4){0.f, 0.f, 0.f, 0.f};   // out^T[v=quad*4+r   ][m=rg*16+l16]
    f32x4 acc1 = acc0;                           // out^T[v=16+quad*4+r][m=rg*16+l16]
    float ps0 = 0.f;

    for (int s = 0; s < 32; ++s) {
        if (s < 30) {   // DMA step s+2 into buffer (s+2)%3
            const int nb = ((s + 2) % 3) * 8192;
#pragma unroll
            for (int jj = 0; jj < 2; ++jj) {
                gl_lds16(gsrc[jj], pool + ldsoff[jj] + nb);
                gsrc[jj] += 2048;
            }
        }
        const char* base = pool + rbase + (s % 3) * 8192;
#pragma unroll
        for (int tloc = 0; tloc < 4; ++tloc) {
            const f16x8 kf = *(const f16x8*)(base + tloc * 1024);
            const f16x8 vv = *(const f16x8*)(base + 4096 + tloc * 1024);
            const f16x4 va0 = {vv[0], vv[1], vv[2], vv[3]};
            const f16x4 va1 = {vv[4], vv[5], vv[6], vv[7]};

            f32x4 s0 = __builtin_amdgcn_mfma_f32_16x16x32_f16(kf, qf, (f32x4){0.f,0.f,0.f,0.f}, 0, 0, 0);
            const float p0 = EXP2(s0[0]), p1 = EXP2(s0[1]), p2 = EXP2(s0[2]), p3 = EXP2(s0[3]);
            ps0 += (p0 + p1) + (p2 + p3);
            auto e0 = __builtin_amdgcn_cvt_pkrtz(p0, p1);
            auto e1 = __builtin_amdgcn_cvt_pkrtz(p2, p3);
            const f16x4 pb = {F16(e0[0]), F16(e0[1]), F16(e1[0]), F16(e1[1])};
            acc0 = __builtin_amdgcn_mfma_f32_16x16x16f16(va0, pb, acc0, 0, 0, 0);
            acc1 = __builtin_amdgcn_mfma_f32_16x16x16f16(va1, pb, acc1, 0, 0, 0);
        }
        // wait for step s+1's loads (issued one full step ago), keep s+2's 2
        // loads in flight across the barrier
        if (s < 30)       asm volatile("s_waitcnt vmcnt(2)\n\ts_barrier" ::: "memory");
        else if (s == 30) asm volatile("s_waitcnt vmcnt(0)\n\ts_barrier" ::: "memory");
        else              asm volatile("s_barrier" ::: "memory");
    }

    // ---- epilogue: 2-way key-split combine in (now free) LDS ----
    float* num = (float*)pool;                 // [64][33]
    float* den = (float*)(pool + 64 * 33 * 4); // [64]
    for (int i = tid; i < 64 * 33 + 64; i += 512) ((float*)pool)[i] = 0.f;
    __syncthreads();

    // sum exp-partials over the 4 quads (score rows live in quads)
    ps0 += __shfl_xor(ps0, 16); ps0 += __shfl_xor(ps0, 32);

    const int m = rg * 16 + l16;
#pragma unroll
    for (int r = 0; r < 4; ++r) {
        atomicAdd(&num[m * 33 + quad * 4 + r], acc0[r]);
        atomicAdd(&num[m * 33 + 16 + quad * 4 + r], acc1[r]);
    }
    if (quad == 0) atomicAdd(&den[m], ps0);
    __syncthreads();

    // store: 64 m x 32 v = 2048 f32 = 512 threads x one float4
    {
        const int mloc = tid >> 3, v4 = (tid & 7) * 4;
        const float inv = 1.0f / den[mloc];
        const float* nr = num + mloc * 33 + v4;
        float4 o = {nr[0] * inv, nr[1] * inv, nr[2] * inv, nr[3] * inv};
        *(float4*)(out + (((size_t)(b << 10) + m0 + mloc) << 8) + n * 32 + v4) = o;
    }
}

// ---------------- launch -----------------------------------------------------
extern "C" void kernel_launch(void* const* d_in, const int* in_sizes, int n_in,
                              void* d_out, int out_size, void* d_ws, size_t ws_size,
                              hipStream_t stream) {
    const float* blob = (const float*)d_in[0];
    const float* wq = (const float*)d_in[1];
    const float* bq = (const float*)d_in[2];
    const float* wk = (const float*)d_in[3];
    const float* bk = (const float*)d_in[4];
    const float* wv = (const float*)d_in[5];
    const float* bv = (const float*)d_in[6];
    float* out = (float*)d_out;

    char* ws = (char*)d_ws;
    _Float16* wt = (_Float16*)(ws);                    //   393,216 B
    _Float16* ko = (_Float16*)(ws + 393216);           // 8,388,608 B
    _Float16* vo = (_Float16*)(ws + 8781824);          // 8,388,608 B
    _Float16* qo = (_Float16*)(ws + 17170432);         // 2,097,152 B

    prep_kernel<<<192, 256, 0, stream>>>(wq, wk, wv, wt);
    proj_kernel<<<576, 256, 0, stream>>>(blob, wt, bq, bk, bv, qo, ko, vo);
    attn_kernel<<<512, 512, 0, stream>>>(qo, ko, vo, out);
}